// Round 12
// baseline (927.899 us; speedup 1.0000x reference)
//
#include <hip/hip_runtime.h>
#include <cstdint>
#include <cstddef>

#define NN 100000
#define D 128
#define NE 800000
#define BN_EPS 1e-5f

#define M4 (4 * NN)     // total buckets (dst-major: dst*4 + hop)
#define CH 1000         // scan chunk (buckets) = 250 pcount dwords
#define NB 400          // M4 / CH
#define GB 782          // ceil(NN/128) row-blocks for MFMA gemms
#define CBLK 3125       // NE/256 blocks for the count lanes

typedef __attribute__((ext_vector_type(4))) float f32x4;
typedef __attribute__((ext_vector_type(2))) float f32x2;
typedef __attribute__((ext_vector_type(8))) short s16x8;   // 8 bf16 in 4 VGPRs

__device__ inline unsigned short f2bf(float f) {           // RNE float->bf16
  unsigned int u = __builtin_bit_cast(unsigned int, f);
  u += 0x7FFFu + ((u >> 16) & 1u);
  return (unsigned short)(u >> 16);
}
__device__ inline float bf2f(unsigned short u) {
  unsigned int x = ((unsigned int)u) << 16;
  return __builtin_bit_cast(float, x);
}
__device__ inline float2 bfpair(unsigned int w) {          // (elem d, elem d+1)
  return make_float2(__builtin_bit_cast(float, w << 16),
                     __builtin_bit_cast(float, w & 0xFFFF0000u));
}
__device__ inline f32x2 ntload2(const float* p) {          // streaming load
  return __builtin_nontemporal_load(reinterpret_cast<const f32x2*>(p));
}

// ---------------------------------------------------------------------------
// Fused front-end: CSR count (all hops) + weight prep (extra blocks on y==0).
__global__ __launch_bounds__(256) void k_front(
    const int* __restrict__ e0, const int* __restrict__ e1,
    const int* __restrict__ e2, const int* __restrict__ e3,
    const float* __restrict__ W1, const float* __restrict__ W2,
    unsigned int* __restrict__ pcount, unsigned char* __restrict__ wrank,
    unsigned short* __restrict__ W1T, unsigned short* __restrict__ W2T) {
  const int h = blockIdx.y;
  if (blockIdx.x < CBLK) {                         // ---- CSR count lane
    const int* e = h == 0 ? e0 : h == 1 ? e1 : h == 2 ? e2 : e3;
    const int eid = blockIdx.x * 256 + threadIdx.x;
    const int dst = e[NE + eid];
    unsigned int old = atomicAdd(&pcount[dst], 1u << (8 * h));
    wrank[h * NE + eid] = (unsigned char)((old >> (8 * h)) & 0xFFu);
    return;
  }
  if (h == 0) {                                    // ---- weight prep lane
    int i = (blockIdx.x - CBLK) * 256 + threadIdx.x;   // [0, 32768)
    int k1 = i >> 8, n1 = i & 255;                 // W1[k1][n1]
    W1T[n1 * 128 + k1] = f2bf(W1[i]);
    int k2 = i >> 7, n2 = i & 127;                 // W2[k2][n2]
    W2T[n2 * 256 + k2] = f2bf(W2[i]);
  }
}

// ---------------------------------------------------------------------------
// chunk sums over packed counts (250 dwords = 1000 buckets per chunk)
__global__ __launch_bounds__(256) void k_scanA(const unsigned int* __restrict__ pcount,
                                               int* __restrict__ bsum) {
  __shared__ int red[256];
  const int b = blockIdx.x, t = threadIdx.x;
  int s = 0;
  if (t < 250) {
    unsigned int p = pcount[b * 250 + t];
    s = (int)((p & 0xFFu) + ((p >> 8) & 0xFFu) + ((p >> 16) & 0xFFu) + (p >> 24));
  }
  red[t] = s; __syncthreads();
  for (int off = 128; off > 0; off >>= 1) {
    if (t < off) red[t] += red[t + off];
    __syncthreads();
  }
  if (t == 0) bsum[b] = red[0];
}

// per-chunk exclusive scan -> offsets (chunk prefix of bsum computed in-block)
__global__ __launch_bounds__(256) void k_scanC(const unsigned int* __restrict__ pcount,
                                               const int* __restrict__ bsum,
                                               int* __restrict__ offsets) {
  __shared__ int cnt[CH];
  __shared__ int part[256];
  __shared__ int red[256];
  const int b = blockIdx.x, t = threadIdx.x;
  if (t < 250) {
    unsigned int p = pcount[b * 250 + t];
    cnt[t * 4 + 0] = (int)(p & 0xFFu);
    cnt[t * 4 + 1] = (int)((p >> 8) & 0xFFu);
    cnt[t * 4 + 2] = (int)((p >> 16) & 0xFFu);
    cnt[t * 4 + 3] = (int)(p >> 24);
  }
  // block prefix: sum of bsum[i] for i < b (NB=400 entries, L2-hit)
  int s = 0;
  for (int i = t; i < NB; i += 256)
    if (i < b) s += bsum[i];
  red[t] = s; __syncthreads();
  for (int off = 128; off > 0; off >>= 1) {
    if (t < off) red[t] += red[t + off];
    __syncthreads();
  }
  const int bpre_b = red[0];
  __syncthreads();

  int own = 0;
#pragma unroll
  for (int j = 0; j < 4; j++) {
    int idx = t * 4 + j;
    if (idx < CH) own += cnt[idx];
  }
  part[t] = own; __syncthreads();
  for (int off = 1; off < 256; off <<= 1) {        // inclusive scan
    int x = part[t];
    if (t >= off) x += part[t - off];
    __syncthreads(); part[t] = x; __syncthreads();
  }
  int run = bpre_b + part[t] - own;                // exclusive within chunk
#pragma unroll
  for (int j = 0; j < 4; j++) {
    int idx = t * 4 + j;
    if (idx < CH) { offsets[b * CH + idx] = run; run += cnt[idx]; }
  }
  if (b == 0 && t == 0) offsets[M4] = 4 * NE;
}

// placement, atomic-free. hop0 stores eid (src re-derived from e0 in gather);
// hops1-3 store src. Single 4B scatter per edge.
__global__ __launch_bounds__(256) void k_place(
    const int* __restrict__ e0, const int* __restrict__ e1,
    const int* __restrict__ e2, const int* __restrict__ e3,
    const int* __restrict__ offsets, const unsigned char* __restrict__ wrank,
    int* __restrict__ srcs, int* __restrict__ eids) {
  const int h = blockIdx.y;
  const int* e = h == 0 ? e0 : h == 1 ? e1 : h == 2 ? e2 : e3;
  const int eid = blockIdx.x * 256 + threadIdx.x;
  const int dst = e[NE + eid];
  const int pos = offsets[dst * 4 + h] + (int)wrank[h * NE + eid];
  if (h == 0) {
    eids[pos] = eid;
  } else {
    srcs[pos] = e[eid];
  }
}

// ---------------------------------------------------------------------------
// One wave per dst node; 4 select-free hop loops over fp32 x tables
// (R6's measured-best gather); edge_attr via NT loads; bf16 output.
__global__ __launch_bounds__(256) void k_gather(
    const float* __restrict__ x0, const float* __restrict__ x1,
    const float* __restrict__ x2, const float* __restrict__ x3,
    const float* __restrict__ edge_attr, const float* __restrict__ eps,
    const int* __restrict__ e0, const int* __restrict__ offsets,
    const int* __restrict__ srcs, const int* __restrict__ eids,
    unsigned short* __restrict__ result) {
  const int dst  = blockIdx.x * 4 + (threadIdx.x >> 6);   // grid.x = NN/4 exact
  const int lane = threadIdx.x & 63;
  const int d    = lane * 2;

  const int4 ob = *reinterpret_cast<const int4*>(offsets + 4 * dst);
  const int o0 = ob.x, b1 = ob.y, b2 = ob.z, b3 = ob.w;
  const int o4 = offsets[4 * dst + 4];

  float2 h0 = make_float2(0.f, 0.f);
  float2 h1 = make_float2(0.f, 0.f);
  float2 h2 = make_float2(0.f, 0.f);
  float2 h3 = make_float2(0.f, 0.f);

  // ---- hop 0: relu(x0[e0[eid]] + edge_attr[eid]), unroll x4
  {
    int j = o0;
    for (; j + 4 <= b1; j += 4) {
      const int q0 = eids[j], q1 = eids[j + 1], q2 = eids[j + 2], q3 = eids[j + 3];
      const int p0 = e0[q0], p1 = e0[q1], p2 = e0[q2], p3 = e0[q3];
      f32x2 w0 = ntload2(edge_attr + (size_t)q0 * D + d);
      f32x2 w1 = ntload2(edge_attr + (size_t)q1 * D + d);
      f32x2 w2 = ntload2(edge_attr + (size_t)q2 * D + d);
      f32x2 w3 = ntload2(edge_attr + (size_t)q3 * D + d);
      float2 v0 = *reinterpret_cast<const float2*>(x0 + (size_t)p0 * D + d);
      float2 v1 = *reinterpret_cast<const float2*>(x0 + (size_t)p1 * D + d);
      float2 v2 = *reinterpret_cast<const float2*>(x0 + (size_t)p2 * D + d);
      float2 v3 = *reinterpret_cast<const float2*>(x0 + (size_t)p3 * D + d);
      h0.x += fmaxf(v0.x + w0[0], 0.f); h0.y += fmaxf(v0.y + w0[1], 0.f);
      h0.x += fmaxf(v1.x + w1[0], 0.f); h0.y += fmaxf(v1.y + w1[1], 0.f);
      h0.x += fmaxf(v2.x + w2[0], 0.f); h0.y += fmaxf(v2.y + w2[1], 0.f);
      h0.x += fmaxf(v3.x + w3[0], 0.f); h0.y += fmaxf(v3.y + w3[1], 0.f);
    }
    for (; j < b1; ++j) {
      const int q = eids[j];
      const int p = e0[q];
      f32x2 w = ntload2(edge_attr + (size_t)q * D + d);
      float2 v = *reinterpret_cast<const float2*>(x0 + (size_t)p * D + d);
      h0.x += fmaxf(v.x + w[0], 0.f); h0.y += fmaxf(v.y + w[1], 0.f);
    }
  }

#define HOP_LOOP(XP, ACC, BEG, END) do {                                       \
    int j_ = (BEG);                                                            \
    for (; j_ + 4 <= (END); j_ += 4) {                                         \
      const int p0_ = srcs[j_], p1_ = srcs[j_ + 1];                            \
      const int p2_ = srcs[j_ + 2], p3_ = srcs[j_ + 3];                        \
      float2 v0_ = *reinterpret_cast<const float2*>((XP) + (size_t)p0_ * D + d); \
      float2 v1_ = *reinterpret_cast<const float2*>((XP) + (size_t)p1_ * D + d); \
      float2 v2_ = *reinterpret_cast<const float2*>((XP) + (size_t)p2_ * D + d); \
      float2 v3_ = *reinterpret_cast<const float2*>((XP) + (size_t)p3_ * D + d); \
      ACC.x += fmaxf(v0_.x, 0.f); ACC.y += fmaxf(v0_.y, 0.f);                  \
      ACC.x += fmaxf(v1_.x, 0.f); ACC.y += fmaxf(v1_.y, 0.f);                  \
      ACC.x += fmaxf(v2_.x, 0.f); ACC.y += fmaxf(v2_.y, 0.f);                  \
      ACC.x += fmaxf(v3_.x, 0.f); ACC.y += fmaxf(v3_.y, 0.f);                  \
    }                                                                          \
    for (; j_ < (END); ++j_) {                                                 \
      const int p_ = srcs[j_];                                                 \
      float2 v_ = *reinterpret_cast<const float2*>((XP) + (size_t)p_ * D + d); \
      ACC.x += fmaxf(v_.x, 0.f); ACC.y += fmaxf(v_.y, 0.f);                    \
    }                                                                          \
  } while (0)

  HOP_LOOP(x1, h1, b1, b2);
  HOP_LOOP(x2, h2, b2, b3);
  HOP_LOOP(x3, h3, b3, o4);
#undef HOP_LOOP

  float2 e0v = *reinterpret_cast<const float2*>(eps + d);
  float2 s1 = *reinterpret_cast<const float2*>(eps + 1 * D + d);
  float2 s2 = *reinterpret_cast<const float2*>(eps + 2 * D + d);
  float2 s3 = *reinterpret_cast<const float2*>(eps + 3 * D + d);
  float2 s4 = *reinterpret_cast<const float2*>(eps + 4 * D + d);
  float2 xv = *reinterpret_cast<const float2*>(x0 + (size_t)dst * D + d);

  float ax = (1.f + e0v.x) * xv.x + (1.f + s1.x) * h0.x + (1.f + s2.x) * h1.x
           + (1.f + s3.x) * h2.x + (1.f + s4.x) * h3.x;
  float ay = (1.f + e0v.y) * xv.y + (1.f + s1.y) * h0.y + (1.f + s2.y) * h1.y
           + (1.f + s3.y) * h2.y + (1.f + s4.y) * h3.y;

  reinterpret_cast<unsigned int*>(result)[dst * 64 + lane] =
      (unsigned int)f2bf(ax) | ((unsigned int)f2bf(ay) << 16);
}

// ---------------------------------------------------------------------------
// GEMM1 (MFMA): t1b[N,256]bf16 = Ab[N,128]bf16 @ W1T^T  (b1 cancels in BN1)
__global__ __launch_bounds__(512) void k_gemm1(const unsigned short* __restrict__ Ab,
                                               const unsigned short* __restrict__ W1T,
                                               unsigned short* __restrict__ t1b,
                                               float* __restrict__ sums1,
                                               float* __restrict__ sumsq1) {
  __shared__ float ls[256], lq[256];
  const int tid = threadIdx.x;
  if (tid < 256) { ls[tid] = 0.f; lq[tid] = 0.f; }
  __syncthreads();

  const int lane = tid & 63, wave = tid >> 6;
  const int ln = lane & 15, lk = lane >> 4;
  const int m0 = blockIdx.x * 128 + wave * 16;
  const int arow = m0 + ln;
  const bool av = arow < NN;

  f32x4 acc[16];
#pragma unroll
  for (int t = 0; t < 16; t++) acc[t] = (f32x4)0.f;

#pragma unroll
  for (int kk = 0; kk < 4; kk++) {
    const int kb = kk * 32 + lk * 8;
    s16x8 a = (s16x8)(short)0;
    if (av) a = *reinterpret_cast<const s16x8*>(Ab + arow * 128 + kb);
#pragma unroll
    for (int t = 0; t < 16; t++) {
      s16x8 b = *reinterpret_cast<const s16x8*>(W1T + (t * 16 + ln) * 128 + kb);
      acc[t] = __builtin_amdgcn_mfma_f32_16x16x32_bf16(a, b, acc[t], 0, 0, 0);
    }
  }
#pragma unroll
  for (int t = 0; t < 16; t++) {
    float cs = 0.f, cq = 0.f;
#pragma unroll
    for (int r = 0; r < 4; r++) {
      const int row = m0 + lk * 4 + r;
      float v = acc[t][r];
      if (row < NN) t1b[(size_t)row * 256 + t * 16 + ln] = f2bf(v);
      cs += v;                      // rows >= NN have acc == 0 (a zeroed)
      cq = fmaf(v, v, cq);
    }
    atomicAdd(&ls[t * 16 + ln], cs);
    atomicAdd(&lq[t * 16 + ln], cq);
  }
  __syncthreads();
  if (tid < 256) {
    unsafeAtomicAdd(&sums1[tid], ls[tid]);
    unsafeAtomicAdd(&sumsq1[tid], lq[tid]);
  }
}

// ---------------------------------------------------------------------------
// GEMM2 (MFMA): t2b[N,128]bf16 = relu(bn1(t1b))bf16 @ W2T^T (b2 cancels in BN2)
__global__ __launch_bounds__(512) void k_gemm2(const unsigned short* __restrict__ t1b,
                                               const unsigned short* __restrict__ W2T,
                                               const float* __restrict__ sums1,
                                               const float* __restrict__ sumsq1,
                                               const float* __restrict__ bn1_g,
                                               const float* __restrict__ bn1_b,
                                               unsigned short* __restrict__ t2b,
                                               float* __restrict__ sums2,
                                               float* __restrict__ sumsq2) {
  __shared__ float s1s[256], s1h[256];
  __shared__ float ls[128], lq[128];
  const int tid = threadIdx.x;
  if (tid < 256) {
    float mean = sums1[tid] * (1.f / NN);
    float var  = sumsq1[tid] * (1.f / NN) - mean * mean;
    float rs   = rsqrtf(var + BN_EPS);
    float s    = bn1_g[tid] * rs;
    s1s[tid] = s;
    s1h[tid] = bn1_b[tid] - mean * s;
  }
  if (tid < 128) { ls[tid] = 0.f; lq[tid] = 0.f; }
  __syncthreads();

  const int lane = tid & 63, wave = tid >> 6;
  const int ln = lane & 15, lk = lane >> 4;
  const int m0 = blockIdx.x * 128 + wave * 16;
  const int arow = m0 + ln;
  const bool av = arow < NN;

  f32x4 acc[8];
#pragma unroll
  for (int t = 0; t < 8; t++) acc[t] = (f32x4)0.f;

#pragma unroll
  for (int kk = 0; kk < 8; kk++) {
    const int kb = kk * 32 + lk * 8;
    s16x8 raw = (s16x8)(short)0;
    if (av) raw = *reinterpret_cast<const s16x8*>(t1b + (size_t)arow * 256 + kb);
    s16x8 a;
#pragma unroll
    for (int i = 0; i < 8; i++) {
      const int col = kb + i;
      float v = fmaxf(fmaf(s1s[col], bf2f((unsigned short)raw[i]), s1h[col]), 0.f);
      a[i] = (short)f2bf(av ? v : 0.f);
    }
#pragma unroll
    for (int t = 0; t < 8; t++) {
      s16x8 b = *reinterpret_cast<const s16x8*>(W2T + (t * 16 + ln) * 256 + kb);
      acc[t] = __builtin_amdgcn_mfma_f32_16x16x32_bf16(a, b, acc[t], 0, 0, 0);
    }
  }
#pragma unroll
  for (int t = 0; t < 8; t++) {
    float cs = 0.f, cq = 0.f;
#pragma unroll
    for (int r = 0; r < 4; r++) {
      const int row = m0 + lk * 4 + r;
      float v = acc[t][r];
      if (row < NN) {
        t2b[(size_t)row * 128 + t * 16 + ln] = f2bf(v);
        cs += v;
        cq = fmaf(v, v, cq);
      }
    }
    atomicAdd(&ls[t * 16 + ln], cs);
    atomicAdd(&lq[t * 16 + ln], cq);
  }
  __syncthreads();
  if (tid < 128) {
    unsafeAtomicAdd(&sums2[tid], ls[tid]);
    unsafeAtomicAdd(&sumsq2[tid], lq[tid]);
  }
}

// ---------------------------------------------------------------------------
// Column stats of relu(bn2(t2b)) -> sums3/sumsq3. BN2 inlined; u32-pair reads.
__global__ __launch_bounds__(256) void k_colstats3(const unsigned short* __restrict__ X,
                                                   const float* __restrict__ sums2,
                                                   const float* __restrict__ sumsq2,
                                                   const float* __restrict__ bn2_g,
                                                   const float* __restrict__ bn2_b,
                                                   float* __restrict__ sums3,
                                                   float* __restrict__ sumsq3) {
  const long total = (long)NN * 64;                 // u32 units
  const long stride = (long)gridDim.x * 256;
  const long start = (long)blockIdx.x * 256 + threadIdx.x;
  const int c = (int)(start & 63) * 2;
  float m2a = sums2[c] * (1.f / NN),   m2b = sums2[c + 1] * (1.f / NN);
  float va  = sumsq2[c] * (1.f / NN) - m2a * m2a;
  float vb  = sumsq2[c + 1] * (1.f / NN) - m2b * m2b;
  float sa = bn2_g[c] * rsqrtf(va + BN_EPS);
  float sb = bn2_g[c + 1] * rsqrtf(vb + BN_EPS);
  float ha = bn2_b[c] - m2a * sa;
  float hb = bn2_b[c + 1] - m2b * sb;
  float s0 = 0.f, q0 = 0.f, s1 = 0.f, q1 = 0.f;
  const unsigned int* Xu = reinterpret_cast<const unsigned int*>(X);
  for (long idx = start; idx < total; idx += stride) {
    float2 v = bfpair(Xu[idx]);
    float a = fmaxf(fmaf(sa, v.x, ha), 0.f);
    float b = fmaxf(fmaf(sb, v.y, hb), 0.f);
    s0 += a; q0 = fmaf(a, a, q0);
    s1 += b; q1 = fmaf(b, b, q1);
  }
  unsafeAtomicAdd(&sums3[c], s0);
  unsafeAtomicAdd(&sumsq3[c], q0);
  unsafeAtomicAdd(&sums3[c + 1], s1);
  unsafeAtomicAdd(&sumsq3[c + 1], q1);
}

// out = relu(bn3(relu(bn2(t2b)))) -> d_out fp32 (single write to d_out).
__global__ __launch_bounds__(256) void k_final(const unsigned short* __restrict__ t2b,
                                               float* __restrict__ out,
                                               const float* __restrict__ sums2,
                                               const float* __restrict__ sumsq2,
                                               const float* __restrict__ bn2_g,
                                               const float* __restrict__ bn2_b,
                                               const float* __restrict__ sums3,
                                               const float* __restrict__ sumsq3,
                                               const float* __restrict__ bn3_g,
                                               const float* __restrict__ bn3_b) {
  int i2 = blockIdx.x * 256 + threadIdx.x;         // grid = NN*64/256 = 25000
  int c = (i2 & 63) * 2;
  float2 v = bfpair(reinterpret_cast<const unsigned int*>(t2b)[i2]);
  float o[2];
#pragma unroll
  for (int j = 0; j < 2; j++) {
    int cc = c + j;
    float vv = j ? v.y : v.x;
    float m2 = sums2[cc] * (1.f / NN);
    float va2 = sumsq2[cc] * (1.f / NN) - m2 * m2;
    float a2 = bn2_g[cc] * rsqrtf(va2 + BN_EPS);
    float h2 = bn2_b[cc] - m2 * a2;
    float m3 = sums3[cc] * (1.f / NN);
    float va3 = sumsq3[cc] * (1.f / NN) - m3 * m3;
    float a3 = bn3_g[cc] * rsqrtf(va3 + BN_EPS);
    float h3 = bn3_b[cc] - m3 * a3;
    o[j] = fmaxf(fmaf(a3, fmaxf(fmaf(a2, vv, h2), 0.f), h3), 0.f);
  }
  *reinterpret_cast<float2*>(out + (size_t)i2 * 2) = make_float2(o[0], o[1]);
}

// ---------------------------------------------------------------------------
extern "C" void kernel_launch(void* const* d_in, const int* in_sizes, int n_in,
                              void* d_out, int out_size, void* d_ws, size_t ws_size,
                              hipStream_t stream) {
  const float* x0 = (const float*)d_in[0];
  const float* x1 = (const float*)d_in[1];
  const float* x2 = (const float*)d_in[2];
  const float* x3 = (const float*)d_in[3];
  const float* edge_attr = (const float*)d_in[4];
  const int* e0 = (const int*)d_in[5];
  const int* e1 = (const int*)d_in[6];
  const int* e2 = (const int*)d_in[7];
  const int* e3 = (const int*)d_in[8];
  const float* W1 = (const float*)d_in[9];
  // d_in[10] = b1 (cancels in BN1)
  const float* bn1_g = (const float*)d_in[11];
  const float* bn1_b = (const float*)d_in[12];
  const float* W2 = (const float*)d_in[13];
  // d_in[14] = b2 (cancels in BN2)
  const float* bn2_g = (const float*)d_in[15];
  const float* bn2_b = (const float*)d_in[16];
  const float* bn3_g = (const float*)d_in[17];
  const float* bn3_b = (const float*)d_in[18];
  const float* eps = (const float*)d_in[19];

  char* ws = (char*)d_ws;
  // -- explicit byte layout, 256B-aligned regions --
  unsigned short* resultb = (unsigned short*)ws;               // 25,600,000 B
  unsigned short* t2b = resultb;                               // alias (resultb dead after gemm1)
  unsigned short* t1b = (unsigned short*)(ws + 25600000);      // 51,200,000 B
  unsigned short* W1T = (unsigned short*)(ws + 76800000);      // 65,536 B
  unsigned short* W2T = (unsigned short*)(ws + 76865536);      // 65,536 B
  unsigned int* pcount = (unsigned int*)(ws + 76931072);       // 400,000 B
  float* stats = (float*)(ws + 77331072);                      // 4,096 B (contiguous w/ pcount)
  float* sums1  = stats;           // 256
  float* sumsq1 = sums1 + 256;     // 256
  float* sums2  = sumsq1 + 256;    // 128
  float* sumsq2 = sums2 + 128;     // 128
  float* sums3  = sumsq2 + 128;    // 128
  float* sumsq3 = sums3 + 128;     // 128
  unsigned char* wrank = (unsigned char*)(ws + 77335168);      // 3,200,000 B

  // CSR arrays alias the t1b region (dead until k_gemm1 writes t1b)
  int* offsets = (int*)(ws + 25600000);                        // (M4+1)*4 = 1,600,004
  int* bsum    = (int*)(ws + 27200256);                        // 1,600
  int* srcs    = (int*)(ws + 27203584);                        // 12,800,000
  int* eids    = (int*)(ws + 40003584);                        // 12,800,000 (ends 52.8MB < 76.8MB)

  // one memset covers pcount + stats (contiguous)
  hipMemsetAsync(pcount, 0, 404096, stream);

  // fused front-end: CSR count (all hops) + weight prep
  k_front<<<dim3(CBLK + 128, 4), 256, 0, stream>>>(e0, e1, e2, e3, W1, W2,
                                                   pcount, wrank, W1T, W2T);

  // scan + placement
  k_scanA<<<NB, 256, 0, stream>>>(pcount, bsum);
  k_scanC<<<NB, 256, 0, stream>>>(pcount, bsum, offsets);
  k_place<<<dim3(NE / 256, 4), 256, 0, stream>>>(e0, e1, e2, e3, offsets, wrank, srcs, eids);

  // select-free per-hop loops over fp32 x tables (R6 measured-best gather)
  k_gather<<<NN / 4, 256, 0, stream>>>(x0, x1, x2, x3, edge_attr, eps, e0,
                                       offsets, srcs, eids, resultb);

  // MLP + BNs (MFMA GEMMs with fused stats; bn params inlined in consumers)
  k_gemm1<<<GB, 512, 0, stream>>>(resultb, W1T, t1b, sums1, sumsq1);
  k_gemm2<<<GB, 512, 0, stream>>>(t1b, W2T, sums1, sumsq1, bn1_g, bn1_b,
                                  t2b, sums2, sumsq2);
  k_colstats3<<<512, 256, 0, stream>>>(t2b, sums2, sumsq2, bn2_g, bn2_b, sums3, sumsq3);
  k_final<<<25000, 256, 0, stream>>>(t2b, (float*)d_out, sums2, sumsq2, bn2_g, bn2_b,
                                     sums3, sumsq3, bn3_g, bn3_b);
}

// Round 13
// 857.417 us; speedup vs baseline: 1.0822x; 1.0822x over previous
//
#include <hip/hip_runtime.h>
#include <cstdint>
#include <cstddef>

#define NN 100000
#define D 128
#define NE 800000
#define BN_EPS 1e-5f

#define M4 (4 * NN)     // total buckets (dst-major: dst*4 + hop)
#define CH 1000         // scan chunk (buckets) = 250 pcount dwords
#define NB 400          // M4 / CH
#define GB 782          // ceil(NN/128) row-blocks for MFMA gemms
#define CBLK 3125       // NE/256 blocks for the count lanes

typedef __attribute__((ext_vector_type(4))) float f32x4;
typedef __attribute__((ext_vector_type(2))) float f32x2;
typedef __attribute__((ext_vector_type(8))) short s16x8;   // 8 bf16 in 4 VGPRs

__device__ inline unsigned short f2bf(float f) {           // RNE float->bf16
  unsigned int u = __builtin_bit_cast(unsigned int, f);
  u += 0x7FFFu + ((u >> 16) & 1u);
  return (unsigned short)(u >> 16);
}
__device__ inline float bf2f(unsigned short u) {
  unsigned int x = ((unsigned int)u) << 16;
  return __builtin_bit_cast(float, x);
}
__device__ inline f32x2 ntload2(const float* p) {          // streaming load
  return __builtin_nontemporal_load(reinterpret_cast<const f32x2*>(p));
}

// ---------------------------------------------------------------------------
// Fused front-end: CSR count (all hops) + weight prep (extra blocks on y==0).
__global__ __launch_bounds__(256) void k_front(
    const int* __restrict__ e0, const int* __restrict__ e1,
    const int* __restrict__ e2, const int* __restrict__ e3,
    const float* __restrict__ W1, const float* __restrict__ W2,
    unsigned int* __restrict__ pcount, unsigned char* __restrict__ wrank,
    unsigned short* __restrict__ W1T, unsigned short* __restrict__ W2T) {
  const int h = blockIdx.y;
  if (blockIdx.x < CBLK) {                         // ---- CSR count lane
    const int* e = h == 0 ? e0 : h == 1 ? e1 : h == 2 ? e2 : e3;
    const int eid = blockIdx.x * 256 + threadIdx.x;
    const int dst = e[NE + eid];
    unsigned int old = atomicAdd(&pcount[dst], 1u << (8 * h));
    wrank[h * NE + eid] = (unsigned char)((old >> (8 * h)) & 0xFFu);
    return;
  }
  if (h == 0) {                                    // ---- weight prep lane
    int i = (blockIdx.x - CBLK) * 256 + threadIdx.x;   // [0, 32768)
    int k1 = i >> 8, n1 = i & 255;                 // W1[k1][n1]
    W1T[n1 * 128 + k1] = f2bf(W1[i]);
    int k2 = i >> 7, n2 = i & 127;                 // W2[k2][n2]
    W2T[n2 * 256 + k2] = f2bf(W2[i]);
  }
}

// ---------------------------------------------------------------------------
// chunk sums over packed counts (250 dwords = 1000 buckets per chunk)
__global__ __launch_bounds__(256) void k_scanA(const unsigned int* __restrict__ pcount,
                                               int* __restrict__ bsum) {
  __shared__ int red[256];
  const int b = blockIdx.x, t = threadIdx.x;
  int s = 0;
  if (t < 250) {
    unsigned int p = pcount[b * 250 + t];
    s = (int)((p & 0xFFu) + ((p >> 8) & 0xFFu) + ((p >> 16) & 0xFFu) + (p >> 24));
  }
  red[t] = s; __syncthreads();
  for (int off = 128; off > 0; off >>= 1) {
    if (t < off) red[t] += red[t + off];
    __syncthreads();
  }
  if (t == 0) bsum[b] = red[0];
}

// per-chunk exclusive scan -> offsets (chunk prefix of bsum computed in-block)
__global__ __launch_bounds__(256) void k_scanC(const unsigned int* __restrict__ pcount,
                                               const int* __restrict__ bsum,
                                               int* __restrict__ offsets) {
  __shared__ int cnt[CH];
  __shared__ int part[256];
  __shared__ int red[256];
  const int b = blockIdx.x, t = threadIdx.x;
  if (t < 250) {
    unsigned int p = pcount[b * 250 + t];
    cnt[t * 4 + 0] = (int)(p & 0xFFu);
    cnt[t * 4 + 1] = (int)((p >> 8) & 0xFFu);
    cnt[t * 4 + 2] = (int)((p >> 16) & 0xFFu);
    cnt[t * 4 + 3] = (int)(p >> 24);
  }
  // block prefix: sum of bsum[i] for i < b (NB=400 entries, L2-hit)
  int s = 0;
  for (int i = t; i < NB; i += 256)
    if (i < b) s += bsum[i];
  red[t] = s; __syncthreads();
  for (int off = 128; off > 0; off >>= 1) {
    if (t < off) red[t] += red[t + off];
    __syncthreads();
  }
  const int bpre_b = red[0];
  __syncthreads();

  int own = 0;
#pragma unroll
  for (int j = 0; j < 4; j++) {
    int idx = t * 4 + j;
    if (idx < CH) own += cnt[idx];
  }
  part[t] = own; __syncthreads();
  for (int off = 1; off < 256; off <<= 1) {        // inclusive scan
    int x = part[t];
    if (t >= off) x += part[t - off];
    __syncthreads(); part[t] = x; __syncthreads();
  }
  int run = bpre_b + part[t] - own;                // exclusive within chunk
#pragma unroll
  for (int j = 0; j < 4; j++) {
    int idx = t * 4 + j;
    if (idx < CH) { offsets[b * CH + idx] = run; run += cnt[idx]; }
  }
  if (b == 0 && t == 0) offsets[M4] = 4 * NE;
}

// placement, atomic-free. hop0 stores eid (src re-derived from e0 in gather);
// hops1-3 store src. Single 4B scatter per edge.
__global__ __launch_bounds__(256) void k_place(
    const int* __restrict__ e0, const int* __restrict__ e1,
    const int* __restrict__ e2, const int* __restrict__ e3,
    const int* __restrict__ offsets, const unsigned char* __restrict__ wrank,
    int* __restrict__ srcs, int* __restrict__ eids) {
  const int h = blockIdx.y;
  const int* e = h == 0 ? e0 : h == 1 ? e1 : h == 2 ? e2 : e3;
  const int eid = blockIdx.x * 256 + threadIdx.x;
  const int dst = e[NE + eid];
  const int pos = offsets[dst * 4 + h] + (int)wrank[h * NE + eid];
  if (h == 0) {
    eids[pos] = eid;
  } else {
    srcs[pos] = e[eid];
  }
}

// ---------------------------------------------------------------------------
// One wave per dst node; 4 select-free hop loops over fp32 x tables
// (R6's measured-best gather); edge_attr via NT loads; bf16 output.
__global__ __launch_bounds__(256) void k_gather(
    const float* __restrict__ x0, const float* __restrict__ x1,
    const float* __restrict__ x2, const float* __restrict__ x3,
    const float* __restrict__ edge_attr, const float* __restrict__ eps,
    const int* __restrict__ e0, const int* __restrict__ offsets,
    const int* __restrict__ srcs, const int* __restrict__ eids,
    unsigned short* __restrict__ result) {
  const int dst  = blockIdx.x * 4 + (threadIdx.x >> 6);   // grid.x = NN/4 exact
  const int lane = threadIdx.x & 63;
  const int d    = lane * 2;

  const int4 ob = *reinterpret_cast<const int4*>(offsets + 4 * dst);
  const int o0 = ob.x, b1 = ob.y, b2 = ob.z, b3 = ob.w;
  const int o4 = offsets[4 * dst + 4];

  float2 h0 = make_float2(0.f, 0.f);
  float2 h1 = make_float2(0.f, 0.f);
  float2 h2 = make_float2(0.f, 0.f);
  float2 h3 = make_float2(0.f, 0.f);

  // ---- hop 0: relu(x0[e0[eid]] + edge_attr[eid]), unroll x4
  {
    int j = o0;
    for (; j + 4 <= b1; j += 4) {
      const int q0 = eids[j], q1 = eids[j + 1], q2 = eids[j + 2], q3 = eids[j + 3];
      const int p0 = e0[q0], p1 = e0[q1], p2 = e0[q2], p3 = e0[q3];
      f32x2 w0 = ntload2(edge_attr + (size_t)q0 * D + d);
      f32x2 w1 = ntload2(edge_attr + (size_t)q1 * D + d);
      f32x2 w2 = ntload2(edge_attr + (size_t)q2 * D + d);
      f32x2 w3 = ntload2(edge_attr + (size_t)q3 * D + d);
      float2 v0 = *reinterpret_cast<const float2*>(x0 + (size_t)p0 * D + d);
      float2 v1 = *reinterpret_cast<const float2*>(x0 + (size_t)p1 * D + d);
      float2 v2 = *reinterpret_cast<const float2*>(x0 + (size_t)p2 * D + d);
      float2 v3 = *reinterpret_cast<const float2*>(x0 + (size_t)p3 * D + d);
      h0.x += fmaxf(v0.x + w0[0], 0.f); h0.y += fmaxf(v0.y + w0[1], 0.f);
      h0.x += fmaxf(v1.x + w1[0], 0.f); h0.y += fmaxf(v1.y + w1[1], 0.f);
      h0.x += fmaxf(v2.x + w2[0], 0.f); h0.y += fmaxf(v2.y + w2[1], 0.f);
      h0.x += fmaxf(v3.x + w3[0], 0.f); h0.y += fmaxf(v3.y + w3[1], 0.f);
    }
    for (; j < b1; ++j) {
      const int q = eids[j];
      const int p = e0[q];
      f32x2 w = ntload2(edge_attr + (size_t)q * D + d);
      float2 v = *reinterpret_cast<const float2*>(x0 + (size_t)p * D + d);
      h0.x += fmaxf(v.x + w[0], 0.f); h0.y += fmaxf(v.y + w[1], 0.f);
    }
  }

#define HOP_LOOP(XP, ACC, BEG, END) do {                                       \
    int j_ = (BEG);                                                            \
    for (; j_ + 4 <= (END); j_ += 4) {                                         \
      const int p0_ = srcs[j_], p1_ = srcs[j_ + 1];                            \
      const int p2_ = srcs[j_ + 2], p3_ = srcs[j_ + 3];                        \
      float2 v0_ = *reinterpret_cast<const float2*>((XP) + (size_t)p0_ * D + d); \
      float2 v1_ = *reinterpret_cast<const float2*>((XP) + (size_t)p1_ * D + d); \
      float2 v2_ = *reinterpret_cast<const float2*>((XP) + (size_t)p2_ * D + d); \
      float2 v3_ = *reinterpret_cast<const float2*>((XP) + (size_t)p3_ * D + d); \
      ACC.x += fmaxf(v0_.x, 0.f); ACC.y += fmaxf(v0_.y, 0.f);                  \
      ACC.x += fmaxf(v1_.x, 0.f); ACC.y += fmaxf(v1_.y, 0.f);                  \
      ACC.x += fmaxf(v2_.x, 0.f); ACC.y += fmaxf(v2_.y, 0.f);                  \
      ACC.x += fmaxf(v3_.x, 0.f); ACC.y += fmaxf(v3_.y, 0.f);                  \
    }                                                                          \
    for (; j_ < (END); ++j_) {                                                 \
      const int p_ = srcs[j_];                                                 \
      float2 v_ = *reinterpret_cast<const float2*>((XP) + (size_t)p_ * D + d); \
      ACC.x += fmaxf(v_.x, 0.f); ACC.y += fmaxf(v_.y, 0.f);                    \
    }                                                                          \
  } while (0)

  HOP_LOOP(x1, h1, b1, b2);
  HOP_LOOP(x2, h2, b2, b3);
  HOP_LOOP(x3, h3, b3, o4);
#undef HOP_LOOP

  float2 e0v = *reinterpret_cast<const float2*>(eps + d);
  float2 s1 = *reinterpret_cast<const float2*>(eps + 1 * D + d);
  float2 s2 = *reinterpret_cast<const float2*>(eps + 2 * D + d);
  float2 s3 = *reinterpret_cast<const float2*>(eps + 3 * D + d);
  float2 s4 = *reinterpret_cast<const float2*>(eps + 4 * D + d);
  float2 xv = *reinterpret_cast<const float2*>(x0 + (size_t)dst * D + d);

  float ax = (1.f + e0v.x) * xv.x + (1.f + s1.x) * h0.x + (1.f + s2.x) * h1.x
           + (1.f + s3.x) * h2.x + (1.f + s4.x) * h3.x;
  float ay = (1.f + e0v.y) * xv.y + (1.f + s1.y) * h0.y + (1.f + s2.y) * h1.y
           + (1.f + s3.y) * h2.y + (1.f + s4.y) * h3.y;

  reinterpret_cast<unsigned int*>(result)[dst * 64 + lane] =
      (unsigned int)f2bf(ax) | ((unsigned int)f2bf(ay) << 16);
}

// ---------------------------------------------------------------------------
// GEMM1 (MFMA): t1b[N,256]bf16 = Ab[N,128]bf16 @ W1T^T  (b1 cancels in BN1)
__global__ __launch_bounds__(512) void k_gemm1(const unsigned short* __restrict__ Ab,
                                               const unsigned short* __restrict__ W1T,
                                               unsigned short* __restrict__ t1b,
                                               float* __restrict__ sums1,
                                               float* __restrict__ sumsq1) {
  __shared__ float ls[256], lq[256];
  const int tid = threadIdx.x;
  if (tid < 256) { ls[tid] = 0.f; lq[tid] = 0.f; }
  __syncthreads();

  const int lane = tid & 63, wave = tid >> 6;
  const int ln = lane & 15, lk = lane >> 4;
  const int m0 = blockIdx.x * 128 + wave * 16;
  const int arow = m0 + ln;
  const bool av = arow < NN;

  f32x4 acc[16];
#pragma unroll
  for (int t = 0; t < 16; t++) acc[t] = (f32x4)0.f;

#pragma unroll
  for (int kk = 0; kk < 4; kk++) {
    const int kb = kk * 32 + lk * 8;
    s16x8 a = (s16x8)(short)0;
    if (av) a = *reinterpret_cast<const s16x8*>(Ab + arow * 128 + kb);
#pragma unroll
    for (int t = 0; t < 16; t++) {
      s16x8 b = *reinterpret_cast<const s16x8*>(W1T + (t * 16 + ln) * 128 + kb);
      acc[t] = __builtin_amdgcn_mfma_f32_16x16x32_bf16(a, b, acc[t], 0, 0, 0);
    }
  }
#pragma unroll
  for (int t = 0; t < 16; t++) {
    float cs = 0.f, cq = 0.f;
#pragma unroll
    for (int r = 0; r < 4; r++) {
      const int row = m0 + lk * 4 + r;
      float v = acc[t][r];
      if (row < NN) t1b[(size_t)row * 256 + t * 16 + ln] = f2bf(v);
      cs += v;                      // rows >= NN have acc == 0 (a zeroed)
      cq = fmaf(v, v, cq);
    }
    atomicAdd(&ls[t * 16 + ln], cs);
    atomicAdd(&lq[t * 16 + ln], cq);
  }
  __syncthreads();
  if (tid < 256) {
    unsafeAtomicAdd(&sums1[tid], ls[tid]);
    unsafeAtomicAdd(&sumsq1[tid], lq[tid]);
  }
}

// ---------------------------------------------------------------------------
// GEMM2 (MFMA): t2[N,128]fp32 = relu(bn1(t1b))bf16 @ W2T^T (b2 cancels in BN2)
// R6 back end: fp32 C written directly to d_out; fused BN2 stats.
__global__ __launch_bounds__(512) void k_gemm2(const unsigned short* __restrict__ t1b,
                                               const unsigned short* __restrict__ W2T,
                                               const float* __restrict__ sums1,
                                               const float* __restrict__ sumsq1,
                                               const float* __restrict__ bn1_g,
                                               const float* __restrict__ bn1_b,
                                               float* __restrict__ C,
                                               float* __restrict__ sums2,
                                               float* __restrict__ sumsq2) {
  __shared__ float s1s[256], s1h[256];
  __shared__ float ls[128], lq[128];
  const int tid = threadIdx.x;
  if (tid < 256) {
    float mean = sums1[tid] * (1.f / NN);
    float var  = sumsq1[tid] * (1.f / NN) - mean * mean;
    float rs   = rsqrtf(var + BN_EPS);
    float s    = bn1_g[tid] * rs;
    s1s[tid] = s;
    s1h[tid] = bn1_b[tid] - mean * s;
  }
  if (tid < 128) { ls[tid] = 0.f; lq[tid] = 0.f; }
  __syncthreads();

  const int lane = tid & 63, wave = tid >> 6;
  const int ln = lane & 15, lk = lane >> 4;
  const int m0 = blockIdx.x * 128 + wave * 16;
  const int arow = m0 + ln;
  const bool av = arow < NN;

  f32x4 acc[8];
#pragma unroll
  for (int t = 0; t < 8; t++) acc[t] = (f32x4)0.f;

#pragma unroll
  for (int kk = 0; kk < 8; kk++) {
    const int kb = kk * 32 + lk * 8;
    s16x8 raw = (s16x8)(short)0;
    if (av) raw = *reinterpret_cast<const s16x8*>(t1b + (size_t)arow * 256 + kb);
    s16x8 a;
#pragma unroll
    for (int i = 0; i < 8; i++) {
      const int col = kb + i;
      float v = fmaxf(fmaf(s1s[col], bf2f((unsigned short)raw[i]), s1h[col]), 0.f);
      a[i] = (short)f2bf(av ? v : 0.f);
    }
#pragma unroll
    for (int t = 0; t < 8; t++) {
      s16x8 b = *reinterpret_cast<const s16x8*>(W2T + (t * 16 + ln) * 256 + kb);
      acc[t] = __builtin_amdgcn_mfma_f32_16x16x32_bf16(a, b, acc[t], 0, 0, 0);
    }
  }
#pragma unroll
  for (int t = 0; t < 8; t++) {
    float cs = 0.f, cq = 0.f;
#pragma unroll
    for (int r = 0; r < 4; r++) {
      const int row = m0 + lk * 4 + r;
      float v = acc[t][r];
      if (row < NN) {
        C[(size_t)row * 128 + t * 16 + ln] = v;
        cs += v;
        cq = fmaf(v, v, cq);
      }
    }
    atomicAdd(&ls[t * 16 + ln], cs);
    atomicAdd(&lq[t * 16 + ln], cq);
  }
  __syncthreads();
  if (tid < 128) {
    unsafeAtomicAdd(&sums2[tid], ls[tid]);
    unsafeAtomicAdd(&sumsq2[tid], lq[tid]);
  }
}

// ---------------------------------------------------------------------------
// Column stats of relu(bn2(t2)) -> sums3/sumsq3. BN2 scale/shift inlined. (R6)
__global__ __launch_bounds__(256) void k_colstats3(const float* __restrict__ X,
                                                   const float* __restrict__ sums2,
                                                   const float* __restrict__ sumsq2,
                                                   const float* __restrict__ bn2_g,
                                                   const float* __restrict__ bn2_b,
                                                   float* __restrict__ sums3,
                                                   float* __restrict__ sumsq3) {
  const long total = (long)NN * 128;
  const long stride = (long)gridDim.x * 256;
  const long start = (long)blockIdx.x * 256 + threadIdx.x;
  const int c = (int)(start & 127);
  float mean = sums2[c] * (1.f / NN);
  float var  = sumsq2[c] * (1.f / NN) - mean * mean;
  float rs   = rsqrtf(var + BN_EPS);
  float scale = bn2_g[c] * rs;
  float shiftv = bn2_b[c] - mean * scale;
  float s = 0.f, q = 0.f;
  for (long idx = start; idx < total; idx += stride) {
    float v = fmaxf(fmaf(scale, X[idx], shiftv), 0.f);
    s += v;
    q = fmaf(v, v, q);
  }
  unsafeAtomicAdd(&sums3[c], s);
  unsafeAtomicAdd(&sumsq3[c], q);
}

// out = relu(bn3(relu(bn2(t2)))), in place on d_out; BN2/BN3 inlined. (R6)
__global__ __launch_bounds__(256) void k_final(float* __restrict__ t2,
                                               const float* __restrict__ sums2,
                                               const float* __restrict__ sumsq2,
                                               const float* __restrict__ bn2_g,
                                               const float* __restrict__ bn2_b,
                                               const float* __restrict__ sums3,
                                               const float* __restrict__ sumsq3,
                                               const float* __restrict__ bn3_g,
                                               const float* __restrict__ bn3_b) {
  int i4 = blockIdx.x * 256 + threadIdx.x;
  if (i4 >= NN * D / 4) return;
  int d = (i4 & 31) * 4;
  float4 v = reinterpret_cast<float4*>(t2)[i4];
  float o[4];
  float* vv = reinterpret_cast<float*>(&v);
#pragma unroll
  for (int j = 0; j < 4; j++) {
    int c = d + j;
    float m2 = sums2[c] * (1.f / NN);
    float va2 = sumsq2[c] * (1.f / NN) - m2 * m2;
    float r2 = rsqrtf(va2 + BN_EPS);
    float a2 = bn2_g[c] * r2;
    float h2 = bn2_b[c] - m2 * a2;
    float m3 = sums3[c] * (1.f / NN);
    float va3 = sumsq3[c] * (1.f / NN) - m3 * m3;
    float r3 = rsqrtf(va3 + BN_EPS);
    float a3 = bn3_g[c] * r3;
    float h3 = bn3_b[c] - m3 * a3;
    o[j] = fmaxf(fmaf(a3, fmaxf(fmaf(a2, vv[j], h2), 0.f), h3), 0.f);
  }
  reinterpret_cast<float4*>(t2)[i4] = make_float4(o[0], o[1], o[2], o[3]);
}

// ---------------------------------------------------------------------------
extern "C" void kernel_launch(void* const* d_in, const int* in_sizes, int n_in,
                              void* d_out, int out_size, void* d_ws, size_t ws_size,
                              hipStream_t stream) {
  const float* x0 = (const float*)d_in[0];
  const float* x1 = (const float*)d_in[1];
  const float* x2 = (const float*)d_in[2];
  const float* x3 = (const float*)d_in[3];
  const float* edge_attr = (const float*)d_in[4];
  const int* e0 = (const int*)d_in[5];
  const int* e1 = (const int*)d_in[6];
  const int* e2 = (const int*)d_in[7];
  const int* e3 = (const int*)d_in[8];
  const float* W1 = (const float*)d_in[9];
  // d_in[10] = b1 (cancels in BN1)
  const float* bn1_g = (const float*)d_in[11];
  const float* bn1_b = (const float*)d_in[12];
  const float* W2 = (const float*)d_in[13];
  // d_in[14] = b2 (cancels in BN2)
  const float* bn2_g = (const float*)d_in[15];
  const float* bn2_b = (const float*)d_in[16];
  const float* bn3_g = (const float*)d_in[17];
  const float* bn3_b = (const float*)d_in[18];
  const float* eps = (const float*)d_in[19];

  char* ws = (char*)d_ws;
  // -- explicit byte layout, 256B-aligned regions --
  unsigned short* resultb = (unsigned short*)ws;               // 25,600,000 B
  unsigned short* t1b = (unsigned short*)(ws + 25600000);      // 51,200,000 B
  unsigned short* W1T = (unsigned short*)(ws + 76800000);      // 65,536 B
  unsigned short* W2T = (unsigned short*)(ws + 76865536);      // 65,536 B
  unsigned int* pcount = (unsigned int*)(ws + 76931072);       // 400,000 B
  float* stats = (float*)(ws + 77331072);                      // 4,096 B (contiguous w/ pcount)
  float* sums1  = stats;           // 256
  float* sumsq1 = sums1 + 256;     // 256
  float* sums2  = sumsq1 + 256;    // 128
  float* sumsq2 = sums2 + 128;     // 128
  float* sums3  = sumsq2 + 128;    // 128
  float* sumsq3 = sums3 + 128;     // 128
  unsigned char* wrank = (unsigned char*)(ws + 77335168);      // 3,200,000 B

  // CSR arrays alias the t1b region (dead until k_gemm1 writes t1b)
  int* offsets = (int*)(ws + 25600000);                        // (M4+1)*4 = 1,600,004
  int* bsum    = (int*)(ws + 27200256);                        // 1,600
  int* srcs    = (int*)(ws + 27203584);                        // 12,800,000
  int* eids    = (int*)(ws + 40003584);                        // 12,800,000 (ends 52.8MB < 76.8MB)

  float* t2 = (float*)d_out;                                   // R6 back end: t2 fp32 in d_out

  // one memset covers pcount + stats (contiguous)
  hipMemsetAsync(pcount, 0, 404096, stream);

  // fused front-end: CSR count (all hops) + weight prep
  k_front<<<dim3(CBLK + 128, 4), 256, 0, stream>>>(e0, e1, e2, e3, W1, W2,
                                                   pcount, wrank, W1T, W2T);

  // scan + placement
  k_scanA<<<NB, 256, 0, stream>>>(pcount, bsum);
  k_scanC<<<NB, 256, 0, stream>>>(pcount, bsum, offsets);
  k_place<<<dim3(NE / 256, 4), 256, 0, stream>>>(e0, e1, e2, e3, offsets, wrank, srcs, eids);

  // select-free per-hop loops over fp32 x tables (R6 measured-best gather)
  k_gather<<<NN / 4, 256, 0, stream>>>(x0, x1, x2, x3, edge_attr, eps, e0,
                                       offsets, srcs, eids, resultb);

  // MLP + BNs (R6 back end: gemm2 -> fp32 d_out, colstats3 fp32, in-place final)
  k_gemm1<<<GB, 512, 0, stream>>>(resultb, W1T, t1b, sums1, sumsq1);
  k_gemm2<<<GB, 512, 0, stream>>>(t1b, W2T, sums1, sumsq1, bn1_g, bn1_b,
                                  t2, sums2, sumsq2);
  k_colstats3<<<512, 256, 0, stream>>>(t2, sums2, sumsq2, bn2_g, bn2_b, sums3, sumsq3);
  k_final<<<NN * D / 4 / 256, 256, 0, stream>>>(t2, sums2, sumsq2, bn2_g, bn2_b,
                                                sums3, sumsq3, bn3_g, bn3_b);
}